// Round 7
// baseline (802.737 us; speedup 1.0000x reference)
//
#include <hip/hip_runtime.h>
#include <hip/hip_bf16.h>

#define NS_N 4000
#define NT_N 4096
#define NTOT 8096
#define ES_E 64000
#define ET_E 65536
#define ETOT 129536
#define D_IN 128
#define D_H 256
#define CAT_D 896               // 128 + 3*256
#define TMP_D 768               // 3*256 fused layer GEMM output
#define NDUM (NT_N - NS_N)      // 96 dummy sinkhorn rows
#define ALPHA_F 20.0f
#define EPS_F 1e-10f

typedef __attribute__((ext_vector_type(8))) short bf16x8;
typedef __attribute__((ext_vector_type(4))) float f32x4;

__device__ inline short f2bf(float v) {
    __hip_bfloat16 b = __float2bfloat16(v);   // RNE
    return *reinterpret_cast<short*>(&b);
}
__device__ inline float bf2f(short s) {
    __hip_bfloat16 b = *reinterpret_cast<__hip_bfloat16*>(&s);
    return __bfloat162float(b);
}
__device__ inline void splitf(float v, short& hi, short& lo) {
    hi = f2bf(v);
    lo = f2bf(v - bf2f(hi));
}

typedef __attribute__((address_space(1))) const char gas_t;
typedef __attribute__((address_space(3))) char las_t;
__device__ inline void gload16(const short* g, short* l) {
    __builtin_amdgcn_global_load_lds((gas_t*)g, (las_t*)l, 16, 0, 0);
}

// ---------------------------------------------------------------------------
// Split-bf16 MFMA GEMM v4: C[M,N]f32 = (Ahi+Alo)[M,K] @ (Bhi+Blo)^T[N,K].
// - 2-phase double-buffered global_load_lds staging (width 16).
// - LDS bank-swizzle via pre-swizzled GLOBAL source (rule #21):
//   slot(row,seg) = row*4 + ((seg + (row>>1))&3)  (16B units)
//   stage inverse: seg = ((lane&3) - (row>>1)) & 3
//   -> fragment reads span all 8 bank-quads (2-way = free).
// - Swapped MFMA operands: mfma(b,a) => lane&15 = C-row, (lane>>4)*4+reg =
//   C-col -> each lane holds 4 consecutive C columns -> float4 stores.
// - BM template (128 or 64); BN fixed 128; K-step 32; 4 waves (2x2).
// EPI: 0=none, 1=+bias, 2=exp(ALPHA*(v+EPS)). COLSUM: col-sums of the
// post-epilogue tile into colacc (Sinkhorn it0, r=1).
// ---------------------------------------------------------------------------
template<int BM, int EPI, bool COLSUM>
__global__ __launch_bounds__(256) void mfma_gemm_kernel(
    const short* __restrict__ Ahi, const short* __restrict__ Alo,
    const short* __restrict__ Bhi, const short* __restrict__ Blo,
    const float* __restrict__ bias, float* __restrict__ C,
    float* __restrict__ colacc,
    int M, int N, int K, int lda, int ldb, int ldc)
{
    constexpr int MI = BM / 32;        // A frags per wave (128->4, 64->2)
    constexpr int WH = BM / 2;         // wave row span
    __shared__ __align__(16) short sAh[2][BM * 32];
    __shared__ __align__(16) short sAl[2][BM * 32];
    __shared__ __align__(16) short sBh[2][4096];
    __shared__ __align__(16) short sBl[2][4096];
    const int bm = blockIdx.x * BM;
    const int bn = blockIdx.y * 128;
    const int tid = threadIdx.x;
    const int lane = tid & 63, wv = tid >> 6;
    const int wr = wv >> 1, wc = wv & 1;
    const int lr = lane & 15, lg = lane >> 4;

    f32x4 acc[MI][4];
    #pragma unroll
    for (int i = 0; i < MI; ++i)
        #pragma unroll
        for (int j = 0; j < 4; ++j) {
            f32x4 z = {0.f, 0.f, 0.f, 0.f};
            acc[i][j] = z;
        }

    // wave-specialized staging with swizzled source
    auto stage = [&](int buf, int k0) {
        const short* src; short* dst; int rowbase, ld, maxrow;
        if (wv == 0)      { src = Ahi; dst = &sAh[buf][0]; rowbase = bm; ld = lda; maxrow = M - 1; }
        else if (wv == 1) { src = Alo; dst = &sAl[buf][0]; rowbase = bm; ld = lda; maxrow = M - 1; }
        else if (wv == 2) { src = Bhi; dst = &sBh[buf][0]; rowbase = bn; ld = ldb; maxrow = N - 1; }
        else              { src = Blo; dst = &sBl[buf][0]; rowbase = bn; ld = ldb; maxrow = N - 1; }
        const int nq = (wv < 2) ? (BM / 16) : 8;
        #pragma unroll
        for (int q = 0; q < 8; ++q) {
            if (q >= nq) break;
            int row = q * 16 + (lane >> 2);
            int seg = ((lane & 3) - (row >> 1)) & 3;
            int gr = min(rowbase + row, maxrow);
            gload16(src + (size_t)gr * ld + k0 + seg * 8, dst + (q * 64 + lane) * 8);
        }
    };
    // swizzled LDS read offset (shorts) for (row, k-half lg)
    auto ldsoff = [](int row, int g) { return (row * 4 + ((g + (row >> 1)) & 3)) * 8; };

    stage(0, 0);
    __syncthreads();
    int cur = 0;
    const int NTILES = K >> 5;
    for (int t0 = 0; t0 < NTILES; ++t0) {
        if (t0 + 1 < NTILES) stage(cur ^ 1, (t0 + 1) << 5);   // prefetch next tile
        bf16x8 ah[MI], al[MI], bh[4], bl[4];
        #pragma unroll
        for (int i = 0; i < MI; ++i) {
            int oa = ldsoff(wr * WH + i * 16 + lr, lg);
            ah[i] = *reinterpret_cast<const bf16x8*>(&sAh[cur][oa]);
            al[i] = *reinterpret_cast<const bf16x8*>(&sAl[cur][oa]);
        }
        #pragma unroll
        for (int j = 0; j < 4; ++j) {
            int ob = ldsoff(wc * 64 + j * 16 + lr, lg);
            bh[j] = *reinterpret_cast<const bf16x8*>(&sBh[cur][ob]);
            bl[j] = *reinterpret_cast<const bf16x8*>(&sBl[cur][ob]);
        }
        #pragma unroll
        for (int i = 0; i < MI; ++i)
            #pragma unroll
            for (int j = 0; j < 4; ++j) {
                acc[i][j] = __builtin_amdgcn_mfma_f32_16x16x32_bf16(bh[j], ah[i], acc[i][j], 0, 0, 0);
                acc[i][j] = __builtin_amdgcn_mfma_f32_16x16x32_bf16(bl[j], ah[i], acc[i][j], 0, 0, 0);
                acc[i][j] = __builtin_amdgcn_mfma_f32_16x16x32_bf16(bh[j], al[i], acc[i][j], 0, 0, 0);
            }
        __syncthreads();   // drains vmcnt+lgkm; prefetch landed, buffers safe
        cur ^= 1;
    }

    // epilogue: swapped layout -> lane holds C[row = ..+lr][col = ..+lg*4+reg]
    float4 csum[4];
    if (COLSUM) {
        #pragma unroll
        for (int j = 0; j < 4; ++j) csum[j] = make_float4(0.f, 0.f, 0.f, 0.f);
    }
    #pragma unroll
    for (int i = 0; i < MI; ++i) {
        int row = bm + wr * WH + i * 16 + lr;
        if (row < M) {
            #pragma unroll
            for (int j = 0; j < 4; ++j) {
                int col = bn + wc * 64 + j * 16 + lg * 4;
                float4 v = make_float4(acc[i][j][0], acc[i][j][1], acc[i][j][2], acc[i][j][3]);
                if (EPI == 1) {
                    const float4 bb = *reinterpret_cast<const float4*>(&bias[col]);
                    v.x += bb.x; v.y += bb.y; v.z += bb.z; v.w += bb.w;
                }
                if (EPI == 2) {
                    v.x = expf(ALPHA_F * (v.x + EPS_F));
                    v.y = expf(ALPHA_F * (v.y + EPS_F));
                    v.z = expf(ALPHA_F * (v.z + EPS_F));
                    v.w = expf(ALPHA_F * (v.w + EPS_F));
                }
                *reinterpret_cast<float4*>(&C[(size_t)row * ldc + col]) = v;
                if (COLSUM) {
                    csum[j].x += v.x; csum[j].y += v.y; csum[j].z += v.z; csum[j].w += v.w;
                }
            }
        }
    }
    if (COLSUM) {
        #pragma unroll
        for (int j = 0; j < 4; ++j) {
            float4 t = csum[j];
            #pragma unroll
            for (int m = 1; m < 16; m <<= 1) {
                t.x += __shfl_xor(t.x, m); t.y += __shfl_xor(t.y, m);
                t.z += __shfl_xor(t.z, m); t.w += __shfl_xor(t.w, m);
            }
            if (lr == 0) {
                int col = bn + wc * 64 + j * 16 + lg * 4;
                atomicAdd(&colacc[col + 0], t.x);
                atomicAdd(&colacc[col + 1], t.y);
                atomicAdd(&colacc[col + 2], t.z);
                atomicAdd(&colacc[col + 3], t.w);
            }
        }
    }
}

// ---------------------------------------------------------------------------
// prep: zero-init (TSA+CNT_IN+CNT_OUT+TSB) + weight transpose/splits + copy_x
// ---------------------------------------------------------------------------
#define ZERO_N (NT_N + 2 * NTOT + NT_N)   // 24384 ints
__global__ __launch_bounds__(256) void prep_kernel(
    const float* __restrict__ xs, const float* __restrict__ xt,
    const float* __restrict__ W1a, const float* __restrict__ W2a, const float* __restrict__ Wra,
    const float* __restrict__ W1b, const float* __restrict__ W2b, const float* __restrict__ Wrb,
    const float* __restrict__ W1c, const float* __restrict__ W2c, const float* __restrict__ Wrc,
    const float* __restrict__ WF,
    short* __restrict__ WThi0, short* __restrict__ WTlo0,
    short* __restrict__ WThi1, short* __restrict__ WTlo1,
    short* __restrict__ WThi2, short* __restrict__ WTlo2,
    short* __restrict__ WFhi, short* __restrict__ WFlo,
    short* __restrict__ CAThi, short* __restrict__ CATlo,
    int* __restrict__ zbase)
{
    int blk = blockIdx.x;
    const int t = threadIdx.x;
    if (blk < 96) {                       // zero TSA + CNT_IN + CNT_OUT + TSB
        int idx = blk * 256 + t;
        if (idx < ZERO_N) zbase[idx] = 0;
        return;
    }
    blk -= 96;
    if (blk < 384 + 768 + 768) {          // layer weight splits
        const float *W1, *W2, *Wr; short *WThi, *WTlo; int K, idx;
        if (blk < 384)      { W1 = W1a; W2 = W2a; Wr = Wra; WThi = WThi0; WTlo = WTlo0; K = 128; idx = blk * 256 + t; }
        else if (blk < 1152){ W1 = W1b; W2 = W2b; Wr = Wrb; WThi = WThi1; WTlo = WTlo1; K = 256; idx = (blk - 384) * 256 + t; }
        else                { W1 = W1c; W2 = W2c; Wr = Wrc; WThi = WThi2; WTlo = WTlo2; K = 256; idx = (blk - 1152) * 256 + t; }
        int k = idx / TMP_D, c = idx % TMP_D;
        float v = (c < 256) ? W1[k * 256 + c]
                : (c < 512) ? W2[k * 256 + (c - 256)]
                            : Wr[k * 256 + (c - 512)];
        short hi, lo;
        splitf(v, hi, lo);
        WThi[(size_t)c * K + k] = hi;
        WTlo[(size_t)c * K + k] = lo;
        return;
    }
    blk -= 1920;
    if (blk < 896) {                      // final_w split: [896][256] -> WT[256][896]
        int idx = blk * 256 + t;
        int k = idx / D_H, n = idx % D_H;
        short hi, lo;
        splitf(WF[idx], hi, lo);
        WFhi[(size_t)n * CAT_D + k] = hi;
        WFlo[(size_t)n * CAT_D + k] = lo;
        return;
    }
    blk -= 896;
    {                                     // copy_x: 4048 blocks over NTOT*128
        int idx = blk * 256 + t;
        int i = idx >> 7, d = idx & 127;
        float v = (i < NS_N) ? xs[(size_t)i * D_IN + d] : xt[(size_t)(i - NS_N) * D_IN + d];
        short hi, lo;
        splitf(v, hi, lo);
        CAThi[(size_t)i * CAT_D + d] = hi;
        CATlo[(size_t)i * CAT_D + d] = lo;
    }
}

// ---------------------------------------------------------------------------
// CSR build: dir 0 = in-edges (key dst), dir 1 = out-edges (key src)
// ---------------------------------------------------------------------------
__global__ void count2_kernel(const int* __restrict__ es, const int* __restrict__ et,
                              int* __restrict__ cin, int* __restrict__ cout)
{
    int e = blockIdx.x * 256 + threadIdx.x;
    int dir = blockIdx.y;
    int* cnt = dir ? cout : cin;
    if (e < ES_E) {
        int key = dir ? es[e] : es[e + ES_E];
        atomicAdd(&cnt[key], 1);
    } else if (e < ETOT) {
        int e2 = e - ES_E;
        int key = dir ? et[e2] : et[e2 + ET_E];
        atomicAdd(&cnt[key + NS_N], 1);
    }
}

__global__ __launch_bounds__(256) void scan2_kernel(const int* __restrict__ cin,
                                                    const int* __restrict__ cout,
                                                    int* __restrict__ rpin, int* __restrict__ rpout,
                                                    int* __restrict__ curin, int* __restrict__ curout)
{
    const int* cnt = blockIdx.x ? cout : cin;
    int* rowptr = blockIdx.x ? rpout : rpin;
    int* cur = blockIdx.x ? curout : curin;
    __shared__ int sums[256];
    const int t = threadIdx.x;
    const int per = (NTOT + 255) / 256;
    const int lo = t * per, hi = min((t + 1) * per, NTOT);
    int s = 0;
    for (int i = lo; i < hi; ++i) s += cnt[i];
    sums[t] = s;
    __syncthreads();
    for (int off = 1; off < 256; off <<= 1) {
        int v = (t >= off) ? sums[t - off] : 0;
        __syncthreads();
        sums[t] += v;
        __syncthreads();
    }
    int base = (t == 0) ? 0 : sums[t - 1];
    for (int i = lo; i < hi; ++i) { rowptr[i] = base; cur[i] = base; base += cnt[i]; }
    if (t == 255) rowptr[NTOT] = base;
}

__global__ void fill2_kernel(const int* __restrict__ es, const int* __restrict__ et,
                             int* __restrict__ curin, int* __restrict__ curout,
                             int* __restrict__ ciin, int* __restrict__ ciout)
{
    int e = blockIdx.x * 256 + threadIdx.x;
    int dir = blockIdx.y;
    int* cur = dir ? curout : curin;
    int* ci = dir ? ciout : ciin;
    int key, val, off;
    if (e < ES_E) {
        key = dir ? es[e] : es[e + ES_E];
        val = dir ? es[e + ES_E] : es[e];
        off = 0;
    } else if (e < ETOT) {
        int e2 = e - ES_E;
        key = dir ? et[e2] : et[e2 + ET_E];
        val = dir ? et[e2 + ET_E] : et[e2];
        off = NS_N;
    } else return;
    int pos = atomicAdd(&cur[key + off], 1);
    ci[pos] = val + off;
}

// ---------------------------------------------------------------------------
// gather + mean + root + bias + relu -> split bf16 CAT slice
// ---------------------------------------------------------------------------
__global__ __launch_bounds__(256) void gather_combine_kernel(
    const float* __restrict__ TMP,
    const int* __restrict__ rp_in, const int* __restrict__ ci_in,
    const int* __restrict__ rp_out, const int* __restrict__ ci_out,
    const float* __restrict__ br, short* __restrict__ CAThi, short* __restrict__ CATlo,
    int catoff)
{
    int node = blockIdx.x * 4 + (threadIdx.x >> 6);
    if (node >= NTOT) return;
    int d = (threadIdx.x & 63) * 4;

    float4 a1 = make_float4(0.f, 0.f, 0.f, 0.f);
    int b0 = rp_in[node], e0 = rp_in[node + 1];
    for (int e = b0; e < e0; ++e) {
        const float4 v = *reinterpret_cast<const float4*>(&TMP[(size_t)ci_in[e] * TMP_D + d]);
        a1.x += v.x; a1.y += v.y; a1.z += v.z; a1.w += v.w;
    }
    float s1 = 1.f / (float)max(e0 - b0, 1);

    float4 a2 = make_float4(0.f, 0.f, 0.f, 0.f);
    int b1 = rp_out[node], e1 = rp_out[node + 1];
    for (int e = b1; e < e1; ++e) {
        const float4 v = *reinterpret_cast<const float4*>(&TMP[(size_t)ci_out[e] * TMP_D + 256 + d]);
        a2.x += v.x; a2.y += v.y; a2.z += v.z; a2.w += v.w;
    }
    float s2 = 1.f / (float)max(e1 - b1, 1);

    const float4 rt = *reinterpret_cast<const float4*>(&TMP[(size_t)node * TMP_D + 512 + d]);
    const float4 bb = *reinterpret_cast<const float4*>(&br[d]);
    float o[4];
    o[0] = fmaxf(rt.x + bb.x + a1.x * s1 + a2.x * s2, 0.f);
    o[1] = fmaxf(rt.y + bb.y + a1.y * s1 + a2.y * s2, 0.f);
    o[2] = fmaxf(rt.z + bb.z + a1.z * s1 + a2.z * s2, 0.f);
    o[3] = fmaxf(rt.w + bb.w + a1.w * s1 + a2.w * s2, 0.f);
    short h[4], l[4];
    #pragma unroll
    for (int q = 0; q < 4; ++q) splitf(o[q], h[q], l[q]);
    *reinterpret_cast<short4*>(&CAThi[(size_t)node * CAT_D + catoff + d]) = make_short4(h[0], h[1], h[2], h[3]);
    *reinterpret_cast<short4*>(&CATlo[(size_t)node * CAT_D + catoff + d]) = make_short4(l[0], l[1], l[2], l[3]);
}

// row L2 normalization -> split bf16; one wave per row
__global__ __launch_bounds__(256) void l2norm_kernel(const float* __restrict__ in,
                                                     short* __restrict__ outhi,
                                                     short* __restrict__ outlo, int N)
{
    int row = blockIdx.x * 4 + (threadIdx.x >> 6);
    if (row >= N) return;
    int d = (threadIdx.x & 63) * 4;
    float4 v = *reinterpret_cast<const float4*>(&in[(size_t)row * D_H + d]);
    float s = v.x * v.x + v.y * v.y + v.z * v.z + v.w * v.w;
    #pragma unroll
    for (int off = 32; off; off >>= 1) s += __shfl_xor(s, off);
    float inv = 1.f / fmaxf(sqrtf(s), 1e-12f);
    float o[4] = {v.x * inv, v.y * inv, v.z * inv, v.w * inv};
    short h[4], l[4];
    #pragma unroll
    for (int q = 0; q < 4; ++q) splitf(o[q], h[q], l[q]);
    *reinterpret_cast<short4*>(&outhi[(size_t)row * D_H + d]) = make_short4(h[0], h[1], h[2], h[3]);
    *reinterpret_cast<short4*>(&outlo[(size_t)row * D_H + d]) = make_short4(l[0], l[1], l[2], l[3]);
}

// ---------------------------------------------------------------------------
// Fused Sinkhorn pass: row-normalize (it 2k+1) + colsum for it 2k+2.
// Block b<500: rows 8b..8b+7. c_j = 1/(tsum_j+dd) once into LDS; per row:
// r_i = 1/sum(v*c), accumulate cacc += r_i*v; one atomic sweep at end.
// Block 500: dummy rd. Blocks 501..516: zero tszero (buffer for NEXT pass).
// OUT variant (last pass, 500 blocks): write out = r_i * v * c instead.
// ---------------------------------------------------------------------------
template<bool FIRST, bool OUT>
__global__ __launch_bounds__(256) void sinkfuse_kernel(
    const float* __restrict__ s0, const float* __restrict__ tsum,
    const float* __restrict__ rdR, float* __restrict__ rdW,
    float* __restrict__ tsnext, float* __restrict__ tszero,
    float* __restrict__ out, float dummyv)
{
    const int bid = blockIdx.x;
    const int t = threadIdx.x;
    if (!OUT && bid >= 501) {             // zero next pass's accum buffer
        tszero[(bid - 501) * 256 + t] = 0.f;
        return;
    }
    __shared__ float4 cl[1024];
    __shared__ float wsred[4];
    const float dd = (float)NDUM * dummyv * (FIRST ? 1.f : rdR[0]);
    const float4* ts4 = reinterpret_cast<const float4*>(tsum);
    #pragma unroll
    for (int k = 0; k < 4; ++k) {
        int j4 = t + k * 256;
        float4 ts = ts4[j4];
        cl[j4] = make_float4(1.f / (ts.x + dd), 1.f / (ts.y + dd),
                             1.f / (ts.z + dd), 1.f / (ts.w + dd));
    }
    __syncthreads();

    if (bid >= 500) {                     // dummy-row block: rd_new
        float s = 0.f;
        #pragma unroll
        for (int k = 0; k < 4; ++k) {
            float4 c = cl[t + k * 256];
            s += c.x + c.y + c.z + c.w;
        }
        #pragma unroll
        for (int m = 1; m < 64; m <<= 1) s += __shfl_xor(s, m);
        if ((t & 63) == 0) wsred[t >> 6] = s;
        __syncthreads();
        if (t == 0) rdW[0] = 1.f / (dummyv * (wsred[0] + wsred[1] + wsred[2] + wsred[3]));
        return;
    }

    float4 cacc[4];
    if (!OUT) {
        #pragma unroll
        for (int k = 0; k < 4; ++k) cacc[k] = make_float4(0.f, 0.f, 0.f, 0.f);
    }
    for (int r8 = 0; r8 < 8; ++r8) {
        int row = bid * 8 + r8;
        const float4* rowp = reinterpret_cast<const float4*>(s0 + (size_t)row * NT_N);
        float4 v[4];
        float s = 0.f;
        #pragma unroll
        for (int k = 0; k < 4; ++k) {
            int j4 = t + k * 256;
            v[k] = rowp[j4];
            float4 c = cl[j4];
            s += v[k].x * c.x + v[k].y * c.y + v[k].z * c.z + v[k].w * c.w;
        }
        #pragma unroll
        for (int m = 1; m < 64; m <<= 1) s += __shfl_xor(s, m);
        if ((t & 63) == 0) wsred[t >> 6] = s;
        __syncthreads();
        float ri = 1.f / (wsred[0] + wsred[1] + wsred[2] + wsred[3]);
        __syncthreads();                  // protect wsred reuse
        if (OUT) {
            float4* outp = reinterpret_cast<float4*>(out + (size_t)row * NT_N);
            #pragma unroll
            for (int k = 0; k < 4; ++k) {
                int j4 = t + k * 256;
                float4 c = cl[j4];
                outp[j4] = make_float4(ri * v[k].x * c.x, ri * v[k].y * c.y,
                                       ri * v[k].z * c.z, ri * v[k].w * c.w);
            }
        } else {
            #pragma unroll
            for (int k = 0; k < 4; ++k) {
                cacc[k].x += ri * v[k].x; cacc[k].y += ri * v[k].y;
                cacc[k].z += ri * v[k].z; cacc[k].w += ri * v[k].w;
            }
        }
    }
    if (!OUT) {
        #pragma unroll
        for (int k = 0; k < 4; ++k) {
            int j = (t + k * 256) * 4;
            atomicAdd(&tsnext[j + 0], cacc[k].x);
            atomicAdd(&tsnext[j + 1], cacc[k].y);
            atomicAdd(&tsnext[j + 2], cacc[k].z);
            atomicAdd(&tsnext[j + 3], cacc[k].w);
        }
    }
}

extern "C" void kernel_launch(void* const* d_in, const int* in_sizes, int n_in,
                              void* d_out, int out_size, void* d_ws, size_t ws_size,
                              hipStream_t stream)
{
    const float* x_s = (const float*)d_in[0];
    const float* x_t = (const float*)d_in[1];
    const int* edges = (const int*)d_in[2];
    const int* edget = (const int*)d_in[3];
    const float* W1[3] = {(const float*)d_in[4], (const float*)d_in[8], (const float*)d_in[12]};
    const float* W2[3] = {(const float*)d_in[5], (const float*)d_in[9], (const float*)d_in[13]};
    const float* Wr[3] = {(const float*)d_in[6], (const float*)d_in[10], (const float*)d_in[14]};
    const float* br[3] = {(const float*)d_in[7], (const float*)d_in[11], (const float*)d_in[15]};
    const float* final_w = (const float*)d_in[16];
    const float* final_b = (const float*)d_in[17];
    float* out = (float*)d_out;

    // ---- workspace layout (float units) ----
    float* W = (float*)d_ws;
    size_t off = 0;
    float* S0 = W + off;  off += (size_t)NS_N * NT_N;                 // 16.38M
    float* TMP = W + off; off += (size_t)NTOT * TMP_D;                // 6.22M
    short* CAThi = (short*)(W + off); off += (size_t)NTOT * CAT_D / 2;
    short* CATlo = (short*)(W + off); off += (size_t)NTOT * CAT_D / 2;
    const int fan[3] = {D_IN, D_H, D_H};
    short* WThi[3]; short* WTlo[3];
    for (int l = 0; l < 3; ++l) {
        WThi[l] = (short*)(W + off); off += (size_t)TMP_D * fan[l] / 2;
        WTlo[l] = (short*)(W + off); off += (size_t)TMP_D * fan[l] / 2;
    }
    short* WFhi = (short*)(W + off); off += (size_t)D_H * CAT_D / 2;
    short* WFlo = (short*)(W + off); off += (size_t)D_H * CAT_D / 2;
    float* RD   = W + off; off += 8;           // rd double buffer
    // contiguous zero-init region: TSA, CNT_IN, CNT_OUT, TSB (prep zeroes)
    float* TSA  = W + off; off += NT_N;
    int* CNT_IN  = (int*)(W + off); off += NTOT;
    int* CNT_OUT = (int*)(W + off); off += NTOT;
    float* TSB  = W + off; off += NT_N;
    float* TSC  = W + off; off += NT_N;
    int* RP_IN   = (int*)(W + off); off += NTOT + 1;
    int* RP_OUT  = (int*)(W + off); off += NTOT + 3;
    int* CUR_IN  = (int*)(W + off); off += NTOT;
    int* CUR_OUT = (int*)(W + off); off += NTOT;
    int* CI_IN   = (int*)(W + off); off += ETOT;
    int* CI_OUT  = (int*)(W + off); off += ETOT;
    float* HFIN = TMP;                                        // [NTOT][256] f32
    short* HNhi = (short*)(TMP + (size_t)NTOT * D_H);         // [NTOT][256] bf16
    short* HNlo = (short*)(TMP + (size_t)NTOT * D_H + (size_t)NTOT * D_H / 2);

    const int cat_off[4] = {0, 128, 384, 640};

    // ---- prep: zero + weight splits + copy_x (one dispatch) ----
    prep_kernel<<<6960, 256, 0, stream>>>(
        x_s, x_t,
        W1[0], W2[0], Wr[0], W1[1], W2[1], Wr[1], W1[2], W2[2], Wr[2], final_w,
        WThi[0], WTlo[0], WThi[1], WTlo[1], WThi[2], WTlo[2], WFhi, WFlo,
        CAThi, CATlo, (int*)TSA);

    // ---- CSR build ----
    {
        dim3 gc((ETOT + 255) / 256, 2);
        count2_kernel<<<gc, 256, 0, stream>>>(edges, edget, CNT_IN, CNT_OUT);
        scan2_kernel<<<2, 256, 0, stream>>>(CNT_IN, CNT_OUT, RP_IN, RP_OUT, CUR_IN, CUR_OUT);
        fill2_kernel<<<gc, 256, 0, stream>>>(edges, edget, CUR_IN, CUR_OUT, CI_IN, CI_OUT);
    }

    // ---- 3 GNN layers ----
    for (int l = 0; l < 3; ++l) {
        dim3 gg((NTOT + 127) / 128, TMP_D / 128);
        mfma_gemm_kernel<128, 0, false><<<gg, 256, 0, stream>>>(
            CAThi + cat_off[l], CATlo + cat_off[l], WThi[l], WTlo[l], nullptr, TMP, nullptr,
            NTOT, TMP_D, fan[l], CAT_D, fan[l], TMP_D);
        gather_combine_kernel<<<(NTOT + 3) / 4, 256, 0, stream>>>(
            TMP, RP_IN, CI_IN, RP_OUT, CI_OUT, br[l], CAThi, CATlo, cat_off[l + 1]);
    }

    // ---- final linear (BM=64: 254 blocks) + l2norm ----
    {
        dim3 gf((NTOT + 63) / 64, D_H / 128);
        mfma_gemm_kernel<64, 1, false><<<gf, 256, 0, stream>>>(
            CAThi, CATlo, WFhi, WFlo, final_b, HFIN, nullptr,
            NTOT, D_H, CAT_D, CAT_D, CAT_D, D_H);
        l2norm_kernel<<<(NTOT + 3) / 4, 256, 0, stream>>>(HFIN, HNhi, HNlo, NTOT);
    }

    // ---- match matrix + fused Sinkhorn it0 colsum (r=1) into TSA ----
    {
        dim3 gm((NS_N + 127) / 128, NT_N / 128);
        mfma_gemm_kernel<128, 2, true><<<gm, 256, 0, stream>>>(
            HNhi, HNlo, HNhi + (size_t)NS_N * D_H, HNlo + (size_t)NS_N * D_H, nullptr, S0, TSA,
            NS_N, NT_N, D_H, D_H, D_H, NT_N);
    }

    // ---- Sinkhorn it1..it9: 5 fused passes (row + next colsum), 3-buf rotation ----
    const float dummyv = expf(ALPHA_F * (EPS_F + EPS_F));
    // F1 = it1+it2: read TSA, acc TSB (prep-zeroed), zero TSC
    sinkfuse_kernel<true, false><<<517, 256, 0, stream>>>(
        S0, TSA, nullptr, &RD[0], TSB, TSC, nullptr, dummyv);
    // F2 = it3+it4: read TSB, acc TSC, zero TSA
    sinkfuse_kernel<false, false><<<517, 256, 0, stream>>>(
        S0, TSB, &RD[0], &RD[1], TSC, TSA, nullptr, dummyv);
    // F3 = it5+it6: read TSC, acc TSA, zero TSB
    sinkfuse_kernel<false, false><<<517, 256, 0, stream>>>(
        S0, TSC, &RD[1], &RD[0], TSA, TSB, nullptr, dummyv);
    // F4 = it7+it8: read TSA, acc TSB, zero TSC
    sinkfuse_kernel<false, false><<<517, 256, 0, stream>>>(
        S0, TSA, &RD[0], &RD[1], TSB, TSC, nullptr, dummyv);
    // F5 = it9 + output
    sinkfuse_kernel<false, true><<<500, 256, 0, stream>>>(
        S0, TSB, &RD[1], nullptr, nullptr, nullptr, out, dummyv);
}